// Round 1
// baseline (780.311 us; speedup 1.0000x reference)
//
#include <hip/hip_runtime.h>

#define NN 50000
#define NE 800000
#define NG 64
#define DF 96
#define SLOPE 0.2f

// ---------------- degree histogram over dst ----------------
__global__ void k_deg(const int* __restrict__ dst, int* __restrict__ deg) {
  int e = blockIdx.x * 256 + threadIdx.x;
  if (e < NE) atomicAdd(&deg[dst[e]], 1);
}

// ---------------- dinv = rsqrt(deg+1); graph node counts ----------------
__global__ void k_dinv(const int* __restrict__ deg, float* __restrict__ dinv,
                       const int* __restrict__ batch, float* __restrict__ gcnt) {
  int n = blockIdx.x * 256 + threadIdx.x;
  if (n < NN) {
    dinv[n] = rsqrtf((float)deg[n] + 1.0f);
    atomicAdd(&gcnt[batch[n]], 1.0f);
  }
}

// ---------------- exclusive prefix sum of deg -> row_start (1 block) ----------------
__global__ __launch_bounds__(1024) void k_scan(const int* __restrict__ deg,
                                               int* __restrict__ row_start) {
  __shared__ int part[1024];
  const int CH = (NN + 1023) / 1024;  // 49
  int t = threadIdx.x;
  int base = t * CH;
  int s = 0;
  for (int i = 0; i < CH; ++i) { int idx = base + i; if (idx < NN) s += deg[idx]; }
  part[t] = s;
  __syncthreads();
  for (int off = 1; off < 1024; off <<= 1) {
    int v = (t >= off) ? part[t - off] : 0;
    __syncthreads();
    part[t] += v;
    __syncthreads();
  }
  int excl = (t == 0) ? 0 : part[t - 1];
  for (int i = 0; i < CH; ++i) {
    int idx = base + i;
    if (idx < NN) { row_start[idx] = excl; excl += deg[idx]; }
  }
  if (t == 1023) row_start[NN] = part[1023];
}

// ---------------- scatter edges into CSR (by dst) ----------------
__global__ void k_scatter(const int* __restrict__ src, const int* __restrict__ dst,
                          const int* __restrict__ row_start, int* __restrict__ cursor,
                          int* __restrict__ csr_src) {
  int e = blockIdx.x * 256 + threadIdx.x;
  if (e < NE) {
    int d = dst[e];
    int p = atomicAdd(&cursor[d], 1);
    csr_src[row_start[d] + p] = src[e];
  }
}

// ---------------- G = (X @ W) * dinv[row]  (fp32, LDS-tiled) ----------------
#define GR 64  // rows per block
__global__ __launch_bounds__(256) void k_gemm(const float* __restrict__ X,
                                              const float* __restrict__ W,
                                              const float* __restrict__ dinv,
                                              float* __restrict__ G) {
  __shared__ float Ws[DF * DF];     // 36864 B
  __shared__ float xs[GR * 100];    // padded stride 100 -> no 4-way bank conflict
  int t = threadIdx.x;
  int rb = blockIdx.x * GR;
  for (int i = t; i < DF * DF / 4; i += 256)
    ((float4*)Ws)[i] = ((const float4*)W)[i];
  for (int i = t; i < GR * DF / 4; i += 256) {
    int r = i / 24, c4 = i % 24;
    int row = rb + r;
    float4 v = (row < NN) ? ((const float4*)(X + (size_t)row * DF))[c4]
                          : float4{0.f, 0.f, 0.f, 0.f};
    *(float4*)&xs[r * 100 + c4 * 4] = v;
  }
  __syncthreads();
  int tc = t & 15;   // 16 col groups x 6 cols
  int tr = t >> 4;   // 16 row groups x 4 rows
  int c0 = tc * 6;
  int r0 = tr * 4;
  float acc[4][6];
#pragma unroll
  for (int i = 0; i < 4; ++i)
#pragma unroll
    for (int j = 0; j < 6; ++j) acc[i][j] = 0.f;

#pragma unroll 4
  for (int k = 0; k < DF; ++k) {
    float xv[4];
#pragma unroll
    for (int i = 0; i < 4; ++i) xv[i] = xs[(r0 + i) * 100 + k];
    float2 w0 = *(float2*)&Ws[k * DF + c0];
    float2 w1 = *(float2*)&Ws[k * DF + c0 + 2];
    float2 w2 = *(float2*)&Ws[k * DF + c0 + 4];
    float wv[6] = {w0.x, w0.y, w1.x, w1.y, w2.x, w2.y};
#pragma unroll
    for (int i = 0; i < 4; ++i)
#pragma unroll
      for (int j = 0; j < 6; ++j) acc[i][j] = fmaf(xv[i], wv[j], acc[i][j]);
  }
#pragma unroll
  for (int i = 0; i < 4; ++i) {
    int row = rb + r0 + i;
    if (row < NN) {
      float dv = dinv[row];
#pragma unroll
      for (int j = 0; j < 6; ++j) G[(size_t)row * DF + c0 + j] = acc[i][j] * dv;
    }
  }
}

// ---------------- gather-aggregate per dst node ----------------
// half-wave (32 lanes) per node; 3 features per lane.
// out[n] = leaky( dinv[n]*(sum_{src->n} g[src] + g[n]) + b )
// FINAL=0: write H.  FINAL=1: atomicAdd into per-graph pooled sums.
template <int FINAL>
__global__ __launch_bounds__(256) void k_agg(const float* __restrict__ G,
                                             const float* __restrict__ dinv,
                                             const float* __restrict__ bias,
                                             const int* __restrict__ row_start,
                                             const int* __restrict__ csr_src,
                                             float* __restrict__ H,
                                             const int* __restrict__ batch,
                                             float* __restrict__ gsum) {
  int lane = threadIdx.x & 31;
  int n = blockIdx.x * 8 + (threadIdx.x >> 5);
  if (n >= NN) return;
  const float* gn = G + (size_t)n * DF;
  float a0 = gn[lane], a1 = gn[lane + 32], a2 = gn[lane + 64];  // self-loop term
  int s = row_start[n], e = row_start[n + 1];
  for (int j0 = s; j0 < e; j0 += 32) {
    int my = (j0 + lane < e) ? csr_src[j0 + lane] : 0;
    int cnt = min(32, e - j0);
    for (int jj = 0; jj < cnt; ++jj) {
      int srcn = __shfl(my, jj, 32);
      const float* gs = G + (size_t)srcn * DF;
      a0 += gs[lane];
      a1 += gs[lane + 32];
      a2 += gs[lane + 64];
    }
  }
  float dv = dinv[n];
  float v0 = dv * a0 + bias[lane];
  float v1 = dv * a1 + bias[lane + 32];
  float v2 = dv * a2 + bias[lane + 64];
  v0 = v0 > 0.f ? v0 : SLOPE * v0;
  v1 = v1 > 0.f ? v1 : SLOPE * v1;
  v2 = v2 > 0.f ? v2 : SLOPE * v2;
  if (FINAL) {
    float* gp = gsum + (size_t)batch[n] * DF;
    atomicAdd(&gp[lane], v0);
    atomicAdd(&gp[lane + 32], v1);
    atomicAdd(&gp[lane + 64], v2);
  } else {
    float* hp = H + (size_t)n * DF;
    hp[lane] = v0;
    hp[lane + 32] = v1;
    hp[lane + 64] = v2;
  }
}

// ---------------- pooled mean @ Wc + bc ----------------
__global__ void k_final(const float* __restrict__ gsum, const float* __restrict__ gcnt,
                        const float* __restrict__ Wc, const float* __restrict__ bc,
                        float* __restrict__ out) {
  int t = threadIdx.x;
  if (t >= NG * 2) return;
  int g = t >> 1, o = t & 1;
  float inv = 1.0f / fmaxf(gcnt[g], 1.0f);
  float s = 0.f;
  for (int c = 0; c < DF; ++c) s += gsum[g * DF + c] * Wc[c * 2 + o];
  out[t] = s * inv + bc[o];
}

extern "C" void kernel_launch(void* const* d_in, const int* in_sizes, int n_in,
                              void* d_out, int out_size, void* d_ws, size_t ws_size,
                              hipStream_t stream) {
  const float* x = (const float*)d_in[0];
  const int* ei = (const int*)d_in[1];
  const int* batch = (const int*)d_in[2];
  const float* W1 = (const float*)d_in[3];
  const float* b1 = (const float*)d_in[4];
  const float* W2 = (const float*)d_in[5];
  const float* b2 = (const float*)d_in[6];
  const float* Wc = (const float*)d_in[7];
  const float* bc = (const float*)d_in[8];
  float* out = (float*)d_out;
  const int* srcv = ei;
  const int* dstv = ei + NE;

  char* p = (char*)d_ws;
  auto alloc = [&](size_t bytes) {
    char* r = p;
    p += (bytes + 255) & ~(size_t)255;
    return r;
  };
  int* deg = (int*)alloc((size_t)2 * NN * sizeof(int));  // deg + cursor contiguous
  int* cursor = deg + NN;
  int* row_start = (int*)alloc((size_t)(NN + 1) * sizeof(int));
  int* csr_src = (int*)alloc((size_t)NE * sizeof(int));
  float* dinv = (float*)alloc((size_t)NN * sizeof(float));
  float* g = (float*)alloc((size_t)NN * DF * sizeof(float));
  float* h = (float*)alloc((size_t)NN * DF * sizeof(float));
  float* gsum = (float*)alloc((size_t)(NG * DF + NG) * sizeof(float));  // + gcnt
  float* gcnt = gsum + NG * DF;

  hipMemsetAsync(deg, 0, (size_t)2 * NN * sizeof(int), stream);
  hipMemsetAsync(gsum, 0, (size_t)(NG * DF + NG) * sizeof(float), stream);

  k_deg<<<(NE + 255) / 256, 256, 0, stream>>>(dstv, deg);
  k_dinv<<<(NN + 255) / 256, 256, 0, stream>>>(deg, dinv, batch, gcnt);
  k_scan<<<1, 1024, 0, stream>>>(deg, row_start);
  k_scatter<<<(NE + 255) / 256, 256, 0, stream>>>(srcv, dstv, row_start, cursor, csr_src);

  k_gemm<<<(NN + GR - 1) / GR, 256, 0, stream>>>(x, W1, dinv, g);
  k_agg<0><<<(NN + 7) / 8, 256, 0, stream>>>(g, dinv, b1, row_start, csr_src, h, batch, gsum);
  k_gemm<<<(NN + GR - 1) / GR, 256, 0, stream>>>(h, W2, dinv, g);
  k_agg<1><<<(NN + 7) / 8, 256, 0, stream>>>(g, dinv, b2, row_start, csr_src, h, batch, gsum);

  k_final<<<1, 128, 0, stream>>>(gsum, gcnt, Wc, bc, out);
}

// Round 2
// 387.624 us; speedup vs baseline: 2.0131x; 2.0131x over previous
//
#include <hip/hip_runtime.h>

#define NN 50000
#define NE 800000
#define NG 64
#define DF 96
#define SLOPE 0.2f

// ---------------- degree histogram over dst ----------------
__global__ void k_deg(const int* __restrict__ dst, int* __restrict__ deg) {
  int e = blockIdx.x * 256 + threadIdx.x;
  if (e < NE) atomicAdd(&deg[dst[e]], 1);
}

// ---------------- dinv = rsqrt(deg+1) ----------------
__global__ void k_dinv(const int* __restrict__ deg, float* __restrict__ dinv) {
  int n = blockIdx.x * 256 + threadIdx.x;
  if (n < NN) dinv[n] = rsqrtf((float)deg[n] + 1.0f);
}

// ---------------- graph boundaries via binary search (batch is sorted) ----------------
__global__ void k_gbounds(const int* __restrict__ batch, int* __restrict__ gstart) {
  int g = threadIdx.x;
  if (g <= NG) {
    int lo = 0, hi = NN;
    while (lo < hi) {
      int mid = (lo + hi) >> 1;
      if (batch[mid] < g) lo = mid + 1; else hi = mid;
    }
    gstart[g] = lo;
  }
}

// ---------------- exclusive prefix sum of deg -> row_start (1 block) ----------------
__global__ __launch_bounds__(1024) void k_scan(const int* __restrict__ deg,
                                               int* __restrict__ row_start) {
  __shared__ int part[1024];
  const int CH = (NN + 1023) / 1024;  // 49
  int t = threadIdx.x;
  int base = t * CH;
  int s = 0;
  for (int i = 0; i < CH; ++i) { int idx = base + i; if (idx < NN) s += deg[idx]; }
  part[t] = s;
  __syncthreads();
  for (int off = 1; off < 1024; off <<= 1) {
    int v = (t >= off) ? part[t - off] : 0;
    __syncthreads();
    part[t] += v;
    __syncthreads();
  }
  int excl = (t == 0) ? 0 : part[t - 1];
  for (int i = 0; i < CH; ++i) {
    int idx = base + i;
    if (idx < NN) { row_start[idx] = excl; excl += deg[idx]; }
  }
  if (t == 1023) row_start[NN] = part[1023];
}

// ---------------- scatter edges into CSR (by dst) ----------------
__global__ void k_scatter(const int* __restrict__ src, const int* __restrict__ dst,
                          const int* __restrict__ row_start, int* __restrict__ cursor,
                          int* __restrict__ csr_src) {
  int e = blockIdx.x * 256 + threadIdx.x;
  if (e < NE) {
    int d = dst[e];
    int p = atomicAdd(&cursor[d], 1);
    csr_src[row_start[d] + p] = src[e];
  }
}

// ---------------- G = (X @ W) * dinv[row]  (fp32, LDS-tiled) ----------------
#define GR 64  // rows per block
__global__ __launch_bounds__(256) void k_gemm(const float* __restrict__ X,
                                              const float* __restrict__ W,
                                              const float* __restrict__ dinv,
                                              float* __restrict__ G) {
  __shared__ float Ws[DF * DF];
  __shared__ float xs[GR * 100];  // padded stride
  int t = threadIdx.x;
  int rb = blockIdx.x * GR;
  for (int i = t; i < DF * DF / 4; i += 256)
    ((float4*)Ws)[i] = ((const float4*)W)[i];
  for (int i = t; i < GR * DF / 4; i += 256) {
    int r = i / 24, c4 = i % 24;
    int row = rb + r;
    float4 v = (row < NN) ? ((const float4*)(X + (size_t)row * DF))[c4]
                          : float4{0.f, 0.f, 0.f, 0.f};
    *(float4*)&xs[r * 100 + c4 * 4] = v;
  }
  __syncthreads();
  int tc = t & 15;
  int tr = t >> 4;
  int c0 = tc * 6;
  int r0 = tr * 4;
  float acc[4][6];
#pragma unroll
  for (int i = 0; i < 4; ++i)
#pragma unroll
    for (int j = 0; j < 6; ++j) acc[i][j] = 0.f;

#pragma unroll 4
  for (int k = 0; k < DF; ++k) {
    float xv[4];
#pragma unroll
    for (int i = 0; i < 4; ++i) xv[i] = xs[(r0 + i) * 100 + k];
    float2 w0 = *(float2*)&Ws[k * DF + c0];
    float2 w1 = *(float2*)&Ws[k * DF + c0 + 2];
    float2 w2 = *(float2*)&Ws[k * DF + c0 + 4];
    float wv[6] = {w0.x, w0.y, w1.x, w1.y, w2.x, w2.y};
#pragma unroll
    for (int i = 0; i < 4; ++i)
#pragma unroll
      for (int j = 0; j < 6; ++j) acc[i][j] = fmaf(xv[i], wv[j], acc[i][j]);
  }
#pragma unroll
  for (int i = 0; i < 4; ++i) {
    int row = rb + r0 + i;
    if (row < NN) {
      float dv = dinv[row];
#pragma unroll
      for (int j = 0; j < 6; ++j) G[(size_t)row * DF + c0 + j] = acc[i][j] * dv;
    }
  }
}

// ---------------- gather-aggregate per dst node (no atomics) ----------------
// half-wave (32 lanes) per node; 3 features per lane.
// H[n] = leaky( dinv[n]*(sum_{src->n} g[src] + g[n]) + b )
__global__ __launch_bounds__(256) void k_agg(const float* __restrict__ G,
                                             const float* __restrict__ dinv,
                                             const float* __restrict__ bias,
                                             const int* __restrict__ row_start,
                                             const int* __restrict__ csr_src,
                                             float* __restrict__ H) {
  int lane = threadIdx.x & 31;
  int n = blockIdx.x * 8 + (threadIdx.x >> 5);
  if (n >= NN) return;
  const float* gn = G + (size_t)n * DF;
  float a0 = gn[lane], a1 = gn[lane + 32], a2 = gn[lane + 64];  // self-loop term
  int s = row_start[n], e = row_start[n + 1];
  for (int j0 = s; j0 < e; j0 += 32) {
    int my = (j0 + lane < e) ? csr_src[j0 + lane] : 0;
    int cnt = min(32, e - j0);
    for (int jj = 0; jj < cnt; ++jj) {
      int srcn = __shfl(my, jj, 32);
      const float* gs = G + (size_t)srcn * DF;
      a0 += gs[lane];
      a1 += gs[lane + 32];
      a2 += gs[lane + 64];
    }
  }
  float dv = dinv[n];
  float v0 = dv * a0 + bias[lane];
  float v1 = dv * a1 + bias[lane + 32];
  float v2 = dv * a2 + bias[lane + 64];
  v0 = v0 > 0.f ? v0 : SLOPE * v0;
  v1 = v1 > 0.f ? v1 : SLOPE * v1;
  v2 = v2 > 0.f ? v2 : SLOPE * v2;
  float* hp = H + (size_t)n * DF;
  hp[lane] = v0;
  hp[lane + 32] = v1;
  hp[lane + 64] = v2;
}

// ---------------- segmented mean pool per graph (no atomics) ----------------
__global__ __launch_bounds__(384) void k_pool(const float* __restrict__ H,
                                              const int* __restrict__ gstart,
                                              float* __restrict__ pooled) {
  int g = blockIdx.x;
  int f = threadIdx.x % DF;
  int r = threadIdx.x / DF;  // 0..3
  int s = gstart[g], e = gstart[g + 1];
  float acc = 0.f;
  for (int n = s + r; n < e; n += 4) acc += H[(size_t)n * DF + f];
  __shared__ float red[4][DF];
  red[r][f] = acc;
  __syncthreads();
  if (r == 0) {
    float v = red[0][f] + red[1][f] + red[2][f] + red[3][f];
    float cnt = (float)(e - s);
    pooled[g * DF + f] = v / fmaxf(cnt, 1.0f);
  }
}

// ---------------- pooled @ Wc + bc ----------------
__global__ void k_final(const float* __restrict__ pooled, const float* __restrict__ Wc,
                        const float* __restrict__ bc, float* __restrict__ out) {
  int t = threadIdx.x;
  if (t >= NG * 2) return;
  int g = t >> 1, o = t & 1;
  float s = 0.f;
  for (int c = 0; c < DF; ++c) s += pooled[g * DF + c] * Wc[c * 2 + o];
  out[t] = s + bc[o];
}

extern "C" void kernel_launch(void* const* d_in, const int* in_sizes, int n_in,
                              void* d_out, int out_size, void* d_ws, size_t ws_size,
                              hipStream_t stream) {
  const float* x = (const float*)d_in[0];
  const int* ei = (const int*)d_in[1];
  const int* batch = (const int*)d_in[2];
  const float* W1 = (const float*)d_in[3];
  const float* b1 = (const float*)d_in[4];
  const float* W2 = (const float*)d_in[5];
  const float* b2 = (const float*)d_in[6];
  const float* Wc = (const float*)d_in[7];
  const float* bc = (const float*)d_in[8];
  float* out = (float*)d_out;
  const int* srcv = ei;
  const int* dstv = ei + NE;

  char* p = (char*)d_ws;
  auto alloc = [&](size_t bytes) {
    char* r = p;
    p += (bytes + 255) & ~(size_t)255;
    return r;
  };
  int* deg = (int*)alloc((size_t)2 * NN * sizeof(int));  // deg + cursor contiguous
  int* cursor = deg + NN;
  int* row_start = (int*)alloc((size_t)(NN + 1) * sizeof(int));
  int* csr_src = (int*)alloc((size_t)NE * sizeof(int));
  float* dinv = (float*)alloc((size_t)NN * sizeof(float));
  int* gstart = (int*)alloc((size_t)(NG + 1) * sizeof(int));
  float* g = (float*)alloc((size_t)NN * DF * sizeof(float));
  float* h = (float*)alloc((size_t)NN * DF * sizeof(float));
  float* pooled = (float*)alloc((size_t)NG * DF * sizeof(float));

  hipMemsetAsync(deg, 0, (size_t)2 * NN * sizeof(int), stream);

  k_deg<<<(NE + 255) / 256, 256, 0, stream>>>(dstv, deg);
  k_dinv<<<(NN + 255) / 256, 256, 0, stream>>>(deg, dinv);
  k_gbounds<<<1, 128, 0, stream>>>(batch, gstart);
  k_scan<<<1, 1024, 0, stream>>>(deg, row_start);
  k_scatter<<<(NE + 255) / 256, 256, 0, stream>>>(srcv, dstv, row_start, cursor, csr_src);

  k_gemm<<<(NN + GR - 1) / GR, 256, 0, stream>>>(x, W1, dinv, g);
  k_agg<<<(NN + 7) / 8, 256, 0, stream>>>(g, dinv, b1, row_start, csr_src, h);
  k_gemm<<<(NN + GR - 1) / GR, 256, 0, stream>>>(h, W2, dinv, g);
  k_agg<<<(NN + 7) / 8, 256, 0, stream>>>(g, dinv, b2, row_start, csr_src, h);

  k_pool<<<NG, 384, 0, stream>>>(h, gstart, pooled);
  k_final<<<1, 128, 0, stream>>>(pooled, Wc, bc, out);
}

// Round 3
// 306.549 us; speedup vs baseline: 2.5455x; 1.2645x over previous
//
#include <hip/hip_runtime.h>

#define NN 50000
#define NE 800000
#define NG 64
#define DF 96
#define SLOPE 0.2f
#define NB 196  // (NN+255)/256

// ---------------- degree histogram over dst ----------------
__global__ void k_deg(const int* __restrict__ dst, int* __restrict__ deg) {
  int e = blockIdx.x * 256 + threadIdx.x;
  if (e < NE) atomicAdd(&deg[dst[e]], 1);
}

// ---------------- dinv = rsqrt(deg+1); block 0 also does graph bounds ----------------
__global__ void k_dinv(const int* __restrict__ deg, float* __restrict__ dinv,
                       const int* __restrict__ batch, int* __restrict__ gstart) {
  int n = blockIdx.x * 256 + threadIdx.x;
  if (n < NN) dinv[n] = rsqrtf((float)deg[n] + 1.0f);
  if (blockIdx.x == 0 && threadIdx.x <= NG) {
    int g = threadIdx.x;
    int lo = 0, hi = NN;
    while (lo < hi) {
      int mid = (lo + hi) >> 1;
      if (batch[mid] < g) lo = mid + 1; else hi = mid;
    }
    gstart[g] = lo;
  }
}

// ---------------- two-level scan: block sums ----------------
__global__ __launch_bounds__(256) void k_bsum(const int* __restrict__ deg,
                                              int* __restrict__ bsum) {
  __shared__ int s[256];
  int t = threadIdx.x;
  int idx = blockIdx.x * 256 + t;
  s[t] = (idx < NN) ? deg[idx] : 0;
  __syncthreads();
  for (int o = 128; o > 0; o >>= 1) {
    if (t < o) s[t] += s[t + o];
    __syncthreads();
  }
  if (t == 0) bsum[blockIdx.x] = s[0];
}

// ---------------- scan of block sums (1 block) ----------------
__global__ __launch_bounds__(256) void k_scanb(const int* __restrict__ bsum,
                                               int* __restrict__ boff,
                                               int* __restrict__ row_start) {
  __shared__ int s[256];
  int t = threadIdx.x;
  s[t] = (t < NB) ? bsum[t] : 0;
  __syncthreads();
  for (int o = 1; o < 256; o <<= 1) {
    int v = (t >= o) ? s[t - o] : 0;
    __syncthreads();
    s[t] += v;
    __syncthreads();
  }
  if (t < NB) boff[t] = (t == 0) ? 0 : s[t - 1];
  if (t == 255) row_start[NN] = s[255];
}

// ---------------- per-block exclusive scan + offset -> row_start ----------------
__global__ __launch_bounds__(256) void k_rowstart(const int* __restrict__ deg,
                                                  const int* __restrict__ boff,
                                                  int* __restrict__ row_start) {
  __shared__ int s[256];
  int t = threadIdx.x;
  int idx = blockIdx.x * 256 + t;
  int v = (idx < NN) ? deg[idx] : 0;
  s[t] = v;
  __syncthreads();
  for (int o = 1; o < 256; o <<= 1) {
    int u = (t >= o) ? s[t - o] : 0;
    __syncthreads();
    s[t] += u;
    __syncthreads();
  }
  if (idx < NN) row_start[idx] = boff[blockIdx.x] + s[t] - v;
}

// ---------------- scatter edges into CSR (by dst) ----------------
__global__ void k_scatter(const int* __restrict__ src, const int* __restrict__ dst,
                          const int* __restrict__ row_start, int* __restrict__ cursor,
                          int* __restrict__ csr_src) {
  int e = blockIdx.x * 256 + threadIdx.x;
  if (e < NE) {
    int d = dst[e];
    int p = atomicAdd(&cursor[d], 1);
    csr_src[row_start[d] + p] = src[e];
  }
}

// ---------------- G = (X @ W) * dinv[row]  (fp32, LDS-tiled) ----------------
#define GR 64  // rows per block
__global__ __launch_bounds__(256) void k_gemm(const float* __restrict__ X,
                                              const float* __restrict__ W,
                                              const float* __restrict__ dinv,
                                              float* __restrict__ G) {
  __shared__ float Ws[DF * DF];
  __shared__ float xs[GR * 100];  // padded stride
  int t = threadIdx.x;
  int rb = blockIdx.x * GR;
  for (int i = t; i < DF * DF / 4; i += 256)
    ((float4*)Ws)[i] = ((const float4*)W)[i];
  for (int i = t; i < GR * DF / 4; i += 256) {
    int r = i / 24, c4 = i % 24;
    int row = rb + r;
    float4 v = (row < NN) ? ((const float4*)(X + (size_t)row * DF))[c4]
                          : float4{0.f, 0.f, 0.f, 0.f};
    *(float4*)&xs[r * 100 + c4 * 4] = v;
  }
  __syncthreads();
  int tc = t & 15;
  int tr = t >> 4;
  int c0 = tc * 6;
  int r0 = tr * 4;
  float acc[4][6];
#pragma unroll
  for (int i = 0; i < 4; ++i)
#pragma unroll
    for (int j = 0; j < 6; ++j) acc[i][j] = 0.f;

#pragma unroll 4
  for (int k = 0; k < DF; ++k) {
    float xv[4];
#pragma unroll
    for (int i = 0; i < 4; ++i) xv[i] = xs[(r0 + i) * 100 + k];
    float2 w0 = *(float2*)&Ws[k * DF + c0];
    float2 w1 = *(float2*)&Ws[k * DF + c0 + 2];
    float2 w2 = *(float2*)&Ws[k * DF + c0 + 4];
    float wv[6] = {w0.x, w0.y, w1.x, w1.y, w2.x, w2.y};
#pragma unroll
    for (int i = 0; i < 4; ++i)
#pragma unroll
      for (int j = 0; j < 6; ++j) acc[i][j] = fmaf(xv[i], wv[j], acc[i][j]);
  }
#pragma unroll
  for (int i = 0; i < 4; ++i) {
    int row = rb + r0 + i;
    if (row < NN) {
      float dv = dinv[row];
#pragma unroll
      for (int j = 0; j < 6; ++j) G[(size_t)row * DF + c0 + j] = acc[i][j] * dv;
    }
  }
}

// ---------------- gather-aggregate per dst node (no atomics) ----------------
__global__ __launch_bounds__(256) void k_agg(const float* __restrict__ G,
                                             const float* __restrict__ dinv,
                                             const float* __restrict__ bias,
                                             const int* __restrict__ row_start,
                                             const int* __restrict__ csr_src,
                                             float* __restrict__ H) {
  int lane = threadIdx.x & 31;
  int n = blockIdx.x * 8 + (threadIdx.x >> 5);
  if (n >= NN) return;
  const float* gn = G + (size_t)n * DF;
  float a0 = gn[lane], a1 = gn[lane + 32], a2 = gn[lane + 64];  // self-loop term
  int s = row_start[n], e = row_start[n + 1];
  for (int j0 = s; j0 < e; j0 += 32) {
    int my = (j0 + lane < e) ? csr_src[j0 + lane] : 0;
    int cnt = min(32, e - j0);
    for (int jj = 0; jj < cnt; ++jj) {
      int srcn = __shfl(my, jj, 32);
      const float* gs = G + (size_t)srcn * DF;
      a0 += gs[lane];
      a1 += gs[lane + 32];
      a2 += gs[lane + 64];
    }
  }
  float dv = dinv[n];
  float v0 = dv * a0 + bias[lane];
  float v1 = dv * a1 + bias[lane + 32];
  float v2 = dv * a2 + bias[lane + 64];
  v0 = v0 > 0.f ? v0 : SLOPE * v0;
  v1 = v1 > 0.f ? v1 : SLOPE * v1;
  v2 = v2 > 0.f ? v2 : SLOPE * v2;
  float* hp = H + (size_t)n * DF;
  hp[lane] = v0;
  hp[lane + 32] = v1;
  hp[lane + 64] = v2;
}

// ---------------- segmented mean pool per graph (no atomics) ----------------
__global__ __launch_bounds__(384) void k_pool(const float* __restrict__ H,
                                              const int* __restrict__ gstart,
                                              float* __restrict__ pooled) {
  int g = blockIdx.x;
  int f = threadIdx.x % DF;
  int r = threadIdx.x / DF;  // 0..3
  int s = gstart[g], e = gstart[g + 1];
  float acc = 0.f;
  for (int n = s + r; n < e; n += 4) acc += H[(size_t)n * DF + f];
  __shared__ float red[4][DF];
  red[r][f] = acc;
  __syncthreads();
  if (r == 0) {
    float v = red[0][f] + red[1][f] + red[2][f] + red[3][f];
    float cnt = (float)(e - s);
    pooled[g * DF + f] = v / fmaxf(cnt, 1.0f);
  }
}

// ---------------- pooled @ Wc + bc ----------------
__global__ void k_final(const float* __restrict__ pooled, const float* __restrict__ Wc,
                        const float* __restrict__ bc, float* __restrict__ out) {
  int t = threadIdx.x;
  if (t >= NG * 2) return;
  int g = t >> 1, o = t & 1;
  float s = 0.f;
  for (int c = 0; c < DF; ++c) s += pooled[g * DF + c] * Wc[c * 2 + o];
  out[t] = s + bc[o];
}

extern "C" void kernel_launch(void* const* d_in, const int* in_sizes, int n_in,
                              void* d_out, int out_size, void* d_ws, size_t ws_size,
                              hipStream_t stream) {
  const float* x = (const float*)d_in[0];
  const int* ei = (const int*)d_in[1];
  const int* batch = (const int*)d_in[2];
  const float* W1 = (const float*)d_in[3];
  const float* b1 = (const float*)d_in[4];
  const float* W2 = (const float*)d_in[5];
  const float* b2 = (const float*)d_in[6];
  const float* Wc = (const float*)d_in[7];
  const float* bc = (const float*)d_in[8];
  float* out = (float*)d_out;
  const int* srcv = ei;
  const int* dstv = ei + NE;

  char* p = (char*)d_ws;
  auto alloc = [&](size_t bytes) {
    char* r = p;
    p += (bytes + 255) & ~(size_t)255;
    return r;
  };
  int* deg = (int*)alloc((size_t)2 * NN * sizeof(int));  // deg + cursor contiguous
  int* cursor = deg + NN;
  int* row_start = (int*)alloc((size_t)(NN + 1) * sizeof(int));
  int* csr_src = (int*)alloc((size_t)NE * sizeof(int));
  float* dinv = (float*)alloc((size_t)NN * sizeof(float));
  int* gstart = (int*)alloc((size_t)(NG + 1) * sizeof(int));
  int* bsum = (int*)alloc((size_t)NB * sizeof(int));
  int* boff = (int*)alloc((size_t)NB * sizeof(int));
  float* g = (float*)alloc((size_t)NN * DF * sizeof(float));
  float* h = (float*)alloc((size_t)NN * DF * sizeof(float));
  float* pooled = (float*)alloc((size_t)NG * DF * sizeof(float));

  hipMemsetAsync(deg, 0, (size_t)2 * NN * sizeof(int), stream);

  k_deg<<<(NE + 255) / 256, 256, 0, stream>>>(dstv, deg);
  k_dinv<<<(NN + 255) / 256, 256, 0, stream>>>(deg, dinv, batch, gstart);
  k_bsum<<<NB, 256, 0, stream>>>(deg, bsum);
  k_scanb<<<1, 256, 0, stream>>>(bsum, boff, row_start);
  k_rowstart<<<NB, 256, 0, stream>>>(deg, boff, row_start);
  k_scatter<<<(NE + 255) / 256, 256, 0, stream>>>(srcv, dstv, row_start, cursor, csr_src);

  k_gemm<<<(NN + GR - 1) / GR, 256, 0, stream>>>(x, W1, dinv, g);
  k_agg<<<(NN + 7) / 8, 256, 0, stream>>>(g, dinv, b1, row_start, csr_src, h);
  k_gemm<<<(NN + GR - 1) / GR, 256, 0, stream>>>(h, W2, dinv, g);
  k_agg<<<(NN + 7) / 8, 256, 0, stream>>>(g, dinv, b2, row_start, csr_src, h);

  k_pool<<<NG, 384, 0, stream>>>(h, gstart, pooled);
  k_final<<<1, 128, 0, stream>>>(pooled, Wc, bc, out);
}

// Round 4
// 196.857 us; speedup vs baseline: 3.9638x; 1.5572x over previous
//
#include <hip/hip_runtime.h>

#define NN 50000
#define NE 800000
#define NG 64
#define DF 96
#define SLOPE 0.2f
#define NBK 196   // (NN+255)/256 buckets of 256 dst nodes
#define PC 12     // pool chunks per graph

// ---------------- pass A1: global histogram over buckets (dst>>8) ----------------
__global__ __launch_bounds__(256) void k_hist(const int* __restrict__ dst,
                                              int* __restrict__ hist_g) {
  __shared__ int h[NBK];
  int t = threadIdx.x;
  if (t < NBK) h[t] = 0;
  __syncthreads();
  int base = blockIdx.x * 4096;
  for (int k = 0; k < 16; ++k) {
    int e = base + k * 256 + t;
    if (e < NE) atomicAdd(&h[dst[e] >> 8], 1);
  }
  __syncthreads();
  if (t < NBK && h[t]) atomicAdd(&hist_g[t], h[t]);
}

// ---------------- scan bucket hist; cursors; graph bounds; row_start[NN] ----------------
__global__ __launch_bounds__(256) void k_scanB(const int* __restrict__ hist_g,
                                               int* __restrict__ bbase,
                                               int* __restrict__ bcur,
                                               const int* __restrict__ batch,
                                               int* __restrict__ gstart,
                                               int* __restrict__ row_start) {
  __shared__ int s[256];
  int t = threadIdx.x;
  s[t] = (t < NBK) ? hist_g[t] : 0;
  __syncthreads();
  for (int o = 1; o < 256; o <<= 1) {
    int v = (t >= o) ? s[t - o] : 0;
    __syncthreads();
    s[t] += v;
    __syncthreads();
  }
  if (t < NBK) {
    int excl = (t == 0) ? 0 : s[t - 1];
    bbase[t] = excl;
    bcur[t] = excl;
  }
  if (t == NBK) bbase[NBK] = NE;
  if (t <= NG) {  // graph boundaries via binary search (batch sorted)
    int g = t, lo = 0, hi = NN;
    while (lo < hi) {
      int mid = (lo + hi) >> 1;
      if (batch[mid] < g) lo = mid + 1; else hi = mid;
    }
    gstart[g] = lo;
  }
  if (t == 255) row_start[NN] = NE;
}

// ---------------- pass A2: bin edges into buckets (LDS staged, packed 4B) ----------------
// packed entry: src | ((dst&255)<<16)   (src < 65536, dst&255 < 256)
__global__ __launch_bounds__(256) void k_bin(const int* __restrict__ src,
                                             const int* __restrict__ dst,
                                             int* __restrict__ bcur,
                                             int* __restrict__ binned) {
  __shared__ int h[NBK], loff[NBK], cur[NBK], gb[NBK];
  __shared__ int tmp[256];
  __shared__ int stage[4096];
  int t = threadIdx.x;
  if (t < NBK) h[t] = 0;
  __syncthreads();
  int base = blockIdx.x * 4096;
  for (int k = 0; k < 16; ++k) {
    int e = base + k * 256 + t;
    if (e < NE) atomicAdd(&h[dst[e] >> 8], 1);
  }
  __syncthreads();
  tmp[t] = (t < NBK) ? h[t] : 0;
  __syncthreads();
  for (int o = 1; o < 256; o <<= 1) {
    int v = (t >= o) ? tmp[t - o] : 0;
    __syncthreads();
    tmp[t] += v;
    __syncthreads();
  }
  if (t < NBK) {
    int excl = (t == 0) ? 0 : tmp[t - 1];
    loff[t] = excl;
    cur[t] = excl;
    gb[t] = atomicAdd(&bcur[t], h[t]);
  }
  __syncthreads();
  for (int k = 0; k < 16; ++k) {
    int e = base + k * 256 + t;
    if (e < NE) {
      int d = dst[e];
      int b = d >> 8;
      int p = atomicAdd(&cur[b], 1);
      stage[p] = src[e] | ((d & 255) << 16);
    }
  }
  __syncthreads();
  int tot = min(4096, NE - base);
  for (int i = t; i < tot; i += 256) {
    int pr = stage[i];
    int b = 0;
    // recover bucket from position: find b with loff[b] <= i < loff[b]+h[b].
    // cheaper: store bucket in unused high bits? bits 24..31 free only for b<256 -> fits!
    b = (unsigned)pr >> 24;  // placeholder, replaced below
    (void)b;
  }
  // NOTE: bucket recovery handled by packing bucket low 8 bits? Not enough bits.
  // Instead do copy-out with a second stage array of buckets.
  __syncthreads();
}

// The above approach needs bucket id at copy-out; simpler correct variant below.
__global__ __launch_bounds__(256) void k_bin2(const int* __restrict__ src,
                                              const int* __restrict__ dst,
                                              int* __restrict__ bcur,
                                              int* __restrict__ binned) {
  __shared__ int h[NBK], loff[NBK], cur[NBK], gb[NBK];
  __shared__ int tmp[256];
  __shared__ int stage[4096];
  __shared__ unsigned char sbk[4096];
  int t = threadIdx.x;
  if (t < NBK) h[t] = 0;
  __syncthreads();
  int base = blockIdx.x * 4096;
  for (int k = 0; k < 16; ++k) {
    int e = base + k * 256 + t;
    if (e < NE) atomicAdd(&h[dst[e] >> 8], 1);
  }
  __syncthreads();
  tmp[t] = (t < NBK) ? h[t] : 0;
  __syncthreads();
  for (int o = 1; o < 256; o <<= 1) {
    int v = (t >= o) ? tmp[t - o] : 0;
    __syncthreads();
    tmp[t] += v;
    __syncthreads();
  }
  if (t < NBK) {
    int excl = (t == 0) ? 0 : tmp[t - 1];
    loff[t] = excl;
    cur[t] = excl;
    gb[t] = atomicAdd(&bcur[t], h[t]);
  }
  __syncthreads();
  for (int k = 0; k < 16; ++k) {
    int e = base + k * 256 + t;
    if (e < NE) {
      int d = dst[e];
      int b = d >> 8;
      int p = atomicAdd(&cur[b], 1);
      stage[p] = src[e] | ((d & 255) << 16);
      sbk[p] = (unsigned char)(b > 255 ? 255 : b);  // NBK=196 < 256, exact
    }
  }
  __syncthreads();
  int tot = min(4096, NE - base);
  for (int i = t; i < tot; i += 256) {
    int b = sbk[i];
    binned[gb[b] + (i - loff[b])] = stage[i];
  }
}

// ---------------- pass B: per-bucket CSR build + deg/dinv/row_start ----------------
__global__ __launch_bounds__(256) void k_csr(const int* __restrict__ binned,
                                             const int* __restrict__ bbase,
                                             float* __restrict__ dinv,
                                             int* __restrict__ row_start,
                                             int* __restrict__ csr_src) {
  __shared__ int h[256], cur[256], tmp[256];
  int t = threadIdx.x;
  int b = blockIdx.x;
  int ebeg = bbase[b], eend = bbase[b + 1];
  h[t] = 0;
  __syncthreads();
  for (int i = ebeg + t; i < eend; i += 256) atomicAdd(&h[(unsigned)binned[i] >> 16], 1);
  __syncthreads();
  tmp[t] = h[t];
  __syncthreads();
  for (int o = 1; o < 256; o <<= 1) {
    int v = (t >= o) ? tmp[t - o] : 0;
    __syncthreads();
    tmp[t] += v;
    __syncthreads();
  }
  int excl = (t == 0) ? 0 : tmp[t - 1];
  int rs = ebeg + excl;
  cur[t] = rs;
  int n = b * 256 + t;
  if (n < NN) {
    row_start[n] = rs;
    dinv[n] = rsqrtf((float)h[t] + 1.0f);
  }
  __syncthreads();
  for (int i = ebeg + t; i < eend; i += 256) {
    int pr = binned[i];
    int p = atomicAdd(&cur[(unsigned)pr >> 16], 1);
    csr_src[p] = pr & 0xFFFF;
  }
}

// ---------------- G = (X @ W) * dinv[row]  (fp32, LDS-tiled) ----------------
#define GR 64
__global__ __launch_bounds__(256) void k_gemm(const float* __restrict__ X,
                                              const float* __restrict__ W,
                                              const float* __restrict__ dinv,
                                              float* __restrict__ G) {
  __shared__ float Ws[DF * DF];
  __shared__ float xs[GR * 100];
  int t = threadIdx.x;
  int rb = blockIdx.x * GR;
  for (int i = t; i < DF * DF / 4; i += 256)
    ((float4*)Ws)[i] = ((const float4*)W)[i];
  for (int i = t; i < GR * DF / 4; i += 256) {
    int r = i / 24, c4 = i % 24;
    int row = rb + r;
    float4 v = (row < NN) ? ((const float4*)(X + (size_t)row * DF))[c4]
                          : float4{0.f, 0.f, 0.f, 0.f};
    *(float4*)&xs[r * 100 + c4 * 4] = v;
  }
  __syncthreads();
  int tc = t & 15;
  int tr = t >> 4;
  int c0 = tc * 6;
  int r0 = tr * 4;
  float acc[4][6];
#pragma unroll
  for (int i = 0; i < 4; ++i)
#pragma unroll
    for (int j = 0; j < 6; ++j) acc[i][j] = 0.f;

#pragma unroll 4
  for (int k = 0; k < DF; ++k) {
    float xv[4];
#pragma unroll
    for (int i = 0; i < 4; ++i) xv[i] = xs[(r0 + i) * 100 + k];
    float2 w0 = *(float2*)&Ws[k * DF + c0];
    float2 w1 = *(float2*)&Ws[k * DF + c0 + 2];
    float2 w2 = *(float2*)&Ws[k * DF + c0 + 4];
    float wv[6] = {w0.x, w0.y, w1.x, w1.y, w2.x, w2.y};
#pragma unroll
    for (int i = 0; i < 4; ++i)
#pragma unroll
      for (int j = 0; j < 6; ++j) acc[i][j] = fmaf(xv[i], wv[j], acc[i][j]);
  }
#pragma unroll
  for (int i = 0; i < 4; ++i) {
    int row = rb + r0 + i;
    if (row < NN) {
      float dv = dinv[row];
#pragma unroll
      for (int j = 0; j < 6; ++j) G[(size_t)row * DF + c0 + j] = acc[i][j] * dv;
    }
  }
}

// ---------------- gather-aggregate per dst node (unroll-4 MLP) ----------------
__global__ __launch_bounds__(256) void k_agg(const float* __restrict__ G,
                                             const float* __restrict__ dinv,
                                             const float* __restrict__ bias,
                                             const int* __restrict__ row_start,
                                             const int* __restrict__ csr_src,
                                             float* __restrict__ H) {
  int lane = threadIdx.x & 31;
  int n = blockIdx.x * 8 + (threadIdx.x >> 5);
  if (n >= NN) return;
  const float* gn = G + (size_t)n * DF;
  float a0 = gn[lane], a1 = gn[lane + 32], a2 = gn[lane + 64];  // self-loop
  int s = row_start[n], e = row_start[n + 1];
  for (int j0 = s; j0 < e; j0 += 32) {
    int my = (j0 + lane < e) ? csr_src[j0 + lane] : 0;
    int cnt = min(32, e - j0);
    int jj = 0;
    for (; jj + 4 <= cnt; jj += 4) {
      const float* p0 = G + (size_t)__shfl(my, jj, 32) * DF;
      const float* p1 = G + (size_t)__shfl(my, jj + 1, 32) * DF;
      const float* p2 = G + (size_t)__shfl(my, jj + 2, 32) * DF;
      const float* p3 = G + (size_t)__shfl(my, jj + 3, 32) * DF;
      float x00 = p0[lane], x01 = p0[lane + 32], x02 = p0[lane + 64];
      float x10 = p1[lane], x11 = p1[lane + 32], x12 = p1[lane + 64];
      float x20 = p2[lane], x21 = p2[lane + 32], x22 = p2[lane + 64];
      float x30 = p3[lane], x31 = p3[lane + 32], x32 = p3[lane + 64];
      a0 += (x00 + x10) + (x20 + x30);
      a1 += (x01 + x11) + (x21 + x31);
      a2 += (x02 + x12) + (x22 + x32);
    }
    for (; jj < cnt; ++jj) {
      const float* p0 = G + (size_t)__shfl(my, jj, 32) * DF;
      a0 += p0[lane];
      a1 += p0[lane + 32];
      a2 += p0[lane + 64];
    }
  }
  float dv = dinv[n];
  float v0 = dv * a0 + bias[lane];
  float v1 = dv * a1 + bias[lane + 32];
  float v2 = dv * a2 + bias[lane + 64];
  v0 = v0 > 0.f ? v0 : SLOPE * v0;
  v1 = v1 > 0.f ? v1 : SLOPE * v1;
  v2 = v2 > 0.f ? v2 : SLOPE * v2;
  float* hp = H + (size_t)n * DF;
  hp[lane] = v0;
  hp[lane + 32] = v1;
  hp[lane + 64] = v2;
}

// ---------------- pool stage 1: 12 chunks per graph ----------------
__global__ __launch_bounds__(384) void k_pool2(const float* __restrict__ H,
                                               const int* __restrict__ gstart,
                                               float* __restrict__ partial) {
  int g = blockIdx.x / PC, c = blockIdx.x % PC;
  int f = threadIdx.x % DF;
  int r = threadIdx.x / DF;  // 0..3
  int s = gstart[g], e = gstart[g + 1];
  int len = (e - s + PC - 1) / PC;
  int cs = s + c * len, ce = min(cs + len, e);
  float acc = 0.f;
  for (int n = cs + r; n < ce; n += 4) acc += H[(size_t)n * DF + f];
  __shared__ float red[4][DF];
  red[r][f] = acc;
  __syncthreads();
  if (r == 0)
    partial[(size_t)blockIdx.x * DF + f] = red[0][f] + red[1][f] + red[2][f] + red[3][f];
}

// ---------------- pool stage 2 + classifier ----------------
__global__ __launch_bounds__(128) void k_pool3(const float* __restrict__ partial,
                                               const int* __restrict__ gstart,
                                               const float* __restrict__ Wc,
                                               const float* __restrict__ bc,
                                               float* __restrict__ out) {
  __shared__ float pm[DF];
  int g = blockIdx.x;
  int t = threadIdx.x;
  if (t < DF) {
    float s = 0.f;
    for (int c = 0; c < PC; ++c) s += partial[(size_t)(g * PC + c) * DF + t];
    float cnt = (float)(gstart[g + 1] - gstart[g]);
    pm[t] = s / fmaxf(cnt, 1.0f);
  }
  __syncthreads();
  if (t < 2) {
    float s = 0.f;
    for (int c = 0; c < DF; ++c) s += pm[c] * Wc[c * 2 + t];
    out[g * 2 + t] = s + bc[t];
  }
}

extern "C" void kernel_launch(void* const* d_in, const int* in_sizes, int n_in,
                              void* d_out, int out_size, void* d_ws, size_t ws_size,
                              hipStream_t stream) {
  const float* x = (const float*)d_in[0];
  const int* ei = (const int*)d_in[1];
  const int* batch = (const int*)d_in[2];
  const float* W1 = (const float*)d_in[3];
  const float* b1 = (const float*)d_in[4];
  const float* W2 = (const float*)d_in[5];
  const float* b2 = (const float*)d_in[6];
  const float* Wc = (const float*)d_in[7];
  const float* bc = (const float*)d_in[8];
  float* out = (float*)d_out;
  const int* srcv = ei;
  const int* dstv = ei + NE;

  char* p = (char*)d_ws;
  auto alloc = [&](size_t bytes) {
    char* r = p;
    p += (bytes + 255) & ~(size_t)255;
    return r;
  };
  int* hist_g = (int*)alloc((size_t)NBK * sizeof(int));
  int* bbase = (int*)alloc((size_t)(NBK + 1) * sizeof(int));
  int* bcur = (int*)alloc((size_t)NBK * sizeof(int));
  int* gstart = (int*)alloc((size_t)(NG + 1) * sizeof(int));
  int* row_start = (int*)alloc((size_t)(NN + 1) * sizeof(int));
  int* binned = (int*)alloc((size_t)NE * sizeof(int));
  int* csr_src = (int*)alloc((size_t)NE * sizeof(int));
  float* dinv = (float*)alloc((size_t)NN * sizeof(float));
  float* g = (float*)alloc((size_t)NN * DF * sizeof(float));
  float* h = (float*)alloc((size_t)NN * DF * sizeof(float));
  float* partial = (float*)alloc((size_t)NG * PC * DF * sizeof(float));

  hipMemsetAsync(hist_g, 0, (size_t)NBK * sizeof(int), stream);

  const int EB = (NE + 4095) / 4096;  // 196 edge blocks
  k_hist<<<EB, 256, 0, stream>>>(dstv, hist_g);
  k_scanB<<<1, 256, 0, stream>>>(hist_g, bbase, bcur, batch, gstart, row_start);
  k_bin2<<<EB, 256, 0, stream>>>(srcv, dstv, bcur, binned);
  k_csr<<<NBK, 256, 0, stream>>>(binned, bbase, dinv, row_start, csr_src);

  k_gemm<<<(NN + GR - 1) / GR, 256, 0, stream>>>(x, W1, dinv, g);
  k_agg<<<(NN + 7) / 8, 256, 0, stream>>>(g, dinv, b1, row_start, csr_src, h);
  k_gemm<<<(NN + GR - 1) / GR, 256, 0, stream>>>(h, W2, dinv, g);
  k_agg<<<(NN + 7) / 8, 256, 0, stream>>>(g, dinv, b2, row_start, csr_src, h);

  k_pool2<<<NG * PC, 384, 0, stream>>>(h, gstart, partial);
  k_pool3<<<NG, 128, 0, stream>>>(partial, gstart, Wc, bc, out);
}

// Round 5
// 169.387 us; speedup vs baseline: 4.6067x; 1.1622x over previous
//
#include <hip/hip_runtime.h>
#include <hip/hip_fp16.h>

#define NN 50000
#define NE 800000
#define NG 64
#define DF 96
#define SLOPE 0.2f
#define NBK 196   // (NN+255)/256 buckets of 256 dst nodes
#define PC 12     // pool chunks per graph

// ---------------- pass A1: global histogram over buckets (dst>>8) ----------------
__global__ __launch_bounds__(256) void k_hist(const int* __restrict__ dst,
                                              int* __restrict__ hist_g) {
  __shared__ int h[NBK];
  int t = threadIdx.x;
  if (t < NBK) h[t] = 0;
  __syncthreads();
  int base = blockIdx.x * 4096;
  for (int k = 0; k < 16; ++k) {
    int e = base + k * 256 + t;
    if (e < NE) atomicAdd(&h[dst[e] >> 8], 1);
  }
  __syncthreads();
  if (t < NBK && h[t]) atomicAdd(&hist_g[t], h[t]);
}

// ---------------- scan bucket hist; cursors; graph bounds ----------------
__global__ __launch_bounds__(256) void k_scanB(const int* __restrict__ hist_g,
                                               int* __restrict__ bbase,
                                               int* __restrict__ bcur,
                                               const int* __restrict__ batch,
                                               int* __restrict__ gstart,
                                               int* __restrict__ row_start) {
  __shared__ int s[256];
  int t = threadIdx.x;
  s[t] = (t < NBK) ? hist_g[t] : 0;
  __syncthreads();
  for (int o = 1; o < 256; o <<= 1) {
    int v = (t >= o) ? s[t - o] : 0;
    __syncthreads();
    s[t] += v;
    __syncthreads();
  }
  if (t < NBK) {
    int excl = (t == 0) ? 0 : s[t - 1];
    bbase[t] = excl;
    bcur[t] = excl;
  }
  if (t == NBK) bbase[NBK] = NE;
  if (t <= NG) {
    int g = t, lo = 0, hi = NN;
    while (lo < hi) {
      int mid = (lo + hi) >> 1;
      if (batch[mid] < g) lo = mid + 1; else hi = mid;
    }
    gstart[g] = lo;
  }
  if (t == 255) row_start[NN] = NE;
}

// ---------------- pass A2: bin edges into buckets (LDS staged, packed 4B) ----------------
// packed entry: src | ((dst&255)<<16)
__global__ __launch_bounds__(256) void k_bin2(const int* __restrict__ src,
                                              const int* __restrict__ dst,
                                              int* __restrict__ bcur,
                                              int* __restrict__ binned) {
  __shared__ int h[NBK], loff[NBK], cur[NBK], gb[NBK];
  __shared__ int tmp[256];
  __shared__ int stage[4096];
  __shared__ unsigned char sbk[4096];
  int t = threadIdx.x;
  if (t < NBK) h[t] = 0;
  __syncthreads();
  int base = blockIdx.x * 4096;
  for (int k = 0; k < 16; ++k) {
    int e = base + k * 256 + t;
    if (e < NE) atomicAdd(&h[dst[e] >> 8], 1);
  }
  __syncthreads();
  tmp[t] = (t < NBK) ? h[t] : 0;
  __syncthreads();
  for (int o = 1; o < 256; o <<= 1) {
    int v = (t >= o) ? tmp[t - o] : 0;
    __syncthreads();
    tmp[t] += v;
    __syncthreads();
  }
  if (t < NBK) {
    int excl = (t == 0) ? 0 : tmp[t - 1];
    loff[t] = excl;
    cur[t] = excl;
    gb[t] = atomicAdd(&bcur[t], h[t]);
  }
  __syncthreads();
  for (int k = 0; k < 16; ++k) {
    int e = base + k * 256 + t;
    if (e < NE) {
      int d = dst[e];
      int b = d >> 8;
      int p = atomicAdd(&cur[b], 1);
      stage[p] = src[e] | ((d & 255) << 16);
      sbk[p] = (unsigned char)b;  // NBK=196 < 256
    }
  }
  __syncthreads();
  int tot = min(4096, NE - base);
  for (int i = t; i < tot; i += 256) {
    int b = sbk[i];
    binned[gb[b] + (i - loff[b])] = stage[i];
  }
}

// ---------------- pass B: per-bucket CSR build + deg/dinv/row_start ----------------
__global__ __launch_bounds__(256) void k_csr(const int* __restrict__ binned,
                                             const int* __restrict__ bbase,
                                             float* __restrict__ dinv,
                                             int* __restrict__ row_start,
                                             int* __restrict__ csr_src) {
  __shared__ int h[256], cur[256], tmp[256];
  int t = threadIdx.x;
  int b = blockIdx.x;
  int ebeg = bbase[b], eend = bbase[b + 1];
  h[t] = 0;
  __syncthreads();
  for (int i = ebeg + t; i < eend; i += 256) atomicAdd(&h[(unsigned)binned[i] >> 16], 1);
  __syncthreads();
  tmp[t] = h[t];
  __syncthreads();
  for (int o = 1; o < 256; o <<= 1) {
    int v = (t >= o) ? tmp[t - o] : 0;
    __syncthreads();
    tmp[t] += v;
    __syncthreads();
  }
  int excl = (t == 0) ? 0 : tmp[t - 1];
  int rs = ebeg + excl;
  cur[t] = rs;
  int n = b * 256 + t;
  if (n < NN) {
    row_start[n] = rs;
    dinv[n] = rsqrtf((float)h[t] + 1.0f);
  }
  __syncthreads();
  for (int i = ebeg + t; i < eend; i += 256) {
    int pr = binned[i];
    int p = atomicAdd(&cur[(unsigned)pr >> 16], 1);
    csr_src[p] = pr & 0xFFFF;
  }
}

// ---------------- G(fp16) = (X @ W) * dinv[row] ----------------
#define GR 64
__global__ __launch_bounds__(256) void k_gemm(const float* __restrict__ X,
                                              const float* __restrict__ W,
                                              const float* __restrict__ dinv,
                                              __half* __restrict__ G) {
  __shared__ float Ws[DF * DF];
  __shared__ float xs[GR * 100];
  int t = threadIdx.x;
  int rb = blockIdx.x * GR;
  for (int i = t; i < DF * DF / 4; i += 256)
    ((float4*)Ws)[i] = ((const float4*)W)[i];
  for (int i = t; i < GR * DF / 4; i += 256) {
    int r = i / 24, c4 = i % 24;
    int row = rb + r;
    float4 v = (row < NN) ? ((const float4*)(X + (size_t)row * DF))[c4]
                          : float4{0.f, 0.f, 0.f, 0.f};
    *(float4*)&xs[r * 100 + c4 * 4] = v;
  }
  __syncthreads();
  int tc = t & 15;
  int tr = t >> 4;
  int c0 = tc * 6;
  int r0 = tr * 4;
  float acc[4][6];
#pragma unroll
  for (int i = 0; i < 4; ++i)
#pragma unroll
    for (int j = 0; j < 6; ++j) acc[i][j] = 0.f;

#pragma unroll 4
  for (int k = 0; k < DF; ++k) {
    float xv[4];
#pragma unroll
    for (int i = 0; i < 4; ++i) xv[i] = xs[(r0 + i) * 100 + k];
    float2 w0 = *(float2*)&Ws[k * DF + c0];
    float2 w1 = *(float2*)&Ws[k * DF + c0 + 2];
    float2 w2 = *(float2*)&Ws[k * DF + c0 + 4];
    float wv[6] = {w0.x, w0.y, w1.x, w1.y, w2.x, w2.y};
#pragma unroll
    for (int i = 0; i < 4; ++i)
#pragma unroll
      for (int j = 0; j < 6; ++j) acc[i][j] = fmaf(xv[i], wv[j], acc[i][j]);
  }
#pragma unroll
  for (int i = 0; i < 4; ++i) {
    int row = rb + r0 + i;
    if (row < NN) {
      float dv = dinv[row];
      __half2* gp = (__half2*)(G + (size_t)row * DF + c0);  // c0 even -> 4B aligned
#pragma unroll
      for (int j = 0; j < 3; ++j)
        gp[j] = __floats2half2_rn(acc[i][2 * j] * dv, acc[i][2 * j + 1] * dv);
    }
  }
}

// ---------------- gather-aggregate per dst node: 16 lanes/node, fp16 gathers ----------------
__global__ __launch_bounds__(256) void k_agg(const __half* __restrict__ G,
                                             const float* __restrict__ dinv,
                                             const float* __restrict__ bias,
                                             const int* __restrict__ row_start,
                                             const int* __restrict__ csr_src,
                                             float* __restrict__ H) {
  int lane = threadIdx.x & 15;
  int n = blockIdx.x * 16 + (threadIdx.x >> 4);
  if (n >= NN) return;
  const unsigned* rn = (const unsigned*)(G + (size_t)n * DF);
  unsigned su0 = rn[lane], su1 = rn[lane + 16], su2 = rn[lane + 32];
  float2 f0 = __half22float2(*(__half2*)&su0);
  float2 f1 = __half22float2(*(__half2*)&su1);
  float2 f2 = __half22float2(*(__half2*)&su2);
  float a00 = f0.x, a01 = f0.y, a10 = f1.x, a11 = f1.y, a20 = f2.x, a21 = f2.y;

  int s = row_start[n], e = row_start[n + 1];
  for (int j0 = s; j0 < e; j0 += 16) {
    int my = (j0 + lane < e) ? csr_src[j0 + lane] : 0;
    int cnt = min(16, e - j0);
    int jj = 0;
    for (; jj + 8 <= cnt; jj += 8) {
      unsigned u[8][3];
#pragma unroll
      for (int q = 0; q < 8; ++q) {
        int srcn = __shfl(my, jj + q, 16);
        const unsigned* r2 = (const unsigned*)(G + (size_t)srcn * DF);
        u[q][0] = r2[lane];
        u[q][1] = r2[lane + 16];
        u[q][2] = r2[lane + 32];
      }
#pragma unroll
      for (int q = 0; q < 8; ++q) {
        float2 g0 = __half22float2(*(__half2*)&u[q][0]);
        float2 g1 = __half22float2(*(__half2*)&u[q][1]);
        float2 g2 = __half22float2(*(__half2*)&u[q][2]);
        a00 += g0.x; a01 += g0.y;
        a10 += g1.x; a11 += g1.y;
        a20 += g2.x; a21 += g2.y;
      }
    }
    for (; jj < cnt; ++jj) {
      int srcn = __shfl(my, jj, 16);
      const unsigned* r2 = (const unsigned*)(G + (size_t)srcn * DF);
      unsigned v0 = r2[lane], v1 = r2[lane + 16], v2 = r2[lane + 32];
      float2 g0 = __half22float2(*(__half2*)&v0);
      float2 g1 = __half22float2(*(__half2*)&v1);
      float2 g2 = __half22float2(*(__half2*)&v2);
      a00 += g0.x; a01 += g0.y;
      a10 += g1.x; a11 += g1.y;
      a20 += g2.x; a21 += g2.y;
    }
  }
  float dv = dinv[n];
  float2 b0 = *(const float2*)(bias + 2 * lane);
  float2 b1 = *(const float2*)(bias + 2 * lane + 32);
  float2 b2 = *(const float2*)(bias + 2 * lane + 64);
  float v00 = dv * a00 + b0.x, v01 = dv * a01 + b0.y;
  float v10 = dv * a10 + b1.x, v11 = dv * a11 + b1.y;
  float v20 = dv * a20 + b2.x, v21 = dv * a21 + b2.y;
  v00 = v00 > 0.f ? v00 : SLOPE * v00;
  v01 = v01 > 0.f ? v01 : SLOPE * v01;
  v10 = v10 > 0.f ? v10 : SLOPE * v10;
  v11 = v11 > 0.f ? v11 : SLOPE * v11;
  v20 = v20 > 0.f ? v20 : SLOPE * v20;
  v21 = v21 > 0.f ? v21 : SLOPE * v21;
  float2* hp = (float2*)(H + (size_t)n * DF);
  hp[lane] = float2{v00, v01};
  hp[lane + 16] = float2{v10, v11};
  hp[lane + 32] = float2{v20, v21};
}

// ---------------- pool stage 1: 12 chunks per graph ----------------
__global__ __launch_bounds__(384) void k_pool2(const float* __restrict__ H,
                                               const int* __restrict__ gstart,
                                               float* __restrict__ partial) {
  int g = blockIdx.x / PC, c = blockIdx.x % PC;
  int f = threadIdx.x % DF;
  int r = threadIdx.x / DF;  // 0..3
  int s = gstart[g], e = gstart[g + 1];
  int len = (e - s + PC - 1) / PC;
  int cs = s + c * len, ce = min(cs + len, e);
  float acc = 0.f;
  for (int n = cs + r; n < ce; n += 4) acc += H[(size_t)n * DF + f];
  __shared__ float red[4][DF];
  red[r][f] = acc;
  __syncthreads();
  if (r == 0)
    partial[(size_t)blockIdx.x * DF + f] = red[0][f] + red[1][f] + red[2][f] + red[3][f];
}

// ---------------- pool stage 2 + classifier ----------------
__global__ __launch_bounds__(128) void k_pool3(const float* __restrict__ partial,
                                               const int* __restrict__ gstart,
                                               const float* __restrict__ Wc,
                                               const float* __restrict__ bc,
                                               float* __restrict__ out) {
  __shared__ float pm[DF];
  int g = blockIdx.x;
  int t = threadIdx.x;
  if (t < DF) {
    float s = 0.f;
    for (int c = 0; c < PC; ++c) s += partial[(size_t)(g * PC + c) * DF + t];
    float cnt = (float)(gstart[g + 1] - gstart[g]);
    pm[t] = s / fmaxf(cnt, 1.0f);
  }
  __syncthreads();
  if (t < 2) {
    float s = 0.f;
    for (int c = 0; c < DF; ++c) s += pm[c] * Wc[c * 2 + t];
    out[g * 2 + t] = s + bc[t];
  }
}

extern "C" void kernel_launch(void* const* d_in, const int* in_sizes, int n_in,
                              void* d_out, int out_size, void* d_ws, size_t ws_size,
                              hipStream_t stream) {
  const float* x = (const float*)d_in[0];
  const int* ei = (const int*)d_in[1];
  const int* batch = (const int*)d_in[2];
  const float* W1 = (const float*)d_in[3];
  const float* b1 = (const float*)d_in[4];
  const float* W2 = (const float*)d_in[5];
  const float* b2 = (const float*)d_in[6];
  const float* Wc = (const float*)d_in[7];
  const float* bc = (const float*)d_in[8];
  float* out = (float*)d_out;
  const int* srcv = ei;
  const int* dstv = ei + NE;

  char* p = (char*)d_ws;
  auto alloc = [&](size_t bytes) {
    char* r = p;
    p += (bytes + 255) & ~(size_t)255;
    return r;
  };
  int* hist_g = (int*)alloc((size_t)NBK * sizeof(int));
  int* bbase = (int*)alloc((size_t)(NBK + 1) * sizeof(int));
  int* bcur = (int*)alloc((size_t)NBK * sizeof(int));
  int* gstart = (int*)alloc((size_t)(NG + 1) * sizeof(int));
  int* row_start = (int*)alloc((size_t)(NN + 1) * sizeof(int));
  int* binned = (int*)alloc((size_t)NE * sizeof(int));
  int* csr_src = (int*)alloc((size_t)NE * sizeof(int));
  float* dinv = (float*)alloc((size_t)NN * sizeof(float));
  __half* g = (__half*)alloc((size_t)NN * DF * sizeof(__half));
  float* h = (float*)alloc((size_t)NN * DF * sizeof(float));
  float* partial = (float*)alloc((size_t)NG * PC * DF * sizeof(float));

  hipMemsetAsync(hist_g, 0, (size_t)NBK * sizeof(int), stream);

  const int EB = (NE + 4095) / 4096;  // 196 edge blocks
  k_hist<<<EB, 256, 0, stream>>>(dstv, hist_g);
  k_scanB<<<1, 256, 0, stream>>>(hist_g, bbase, bcur, batch, gstart, row_start);
  k_bin2<<<EB, 256, 0, stream>>>(srcv, dstv, bcur, binned);
  k_csr<<<NBK, 256, 0, stream>>>(binned, bbase, dinv, row_start, csr_src);

  k_gemm<<<(NN + GR - 1) / GR, 256, 0, stream>>>(x, W1, dinv, g);
  k_agg<<<NN / 16, 256, 0, stream>>>(g, dinv, b1, row_start, csr_src, h);
  k_gemm<<<(NN + GR - 1) / GR, 256, 0, stream>>>(h, W2, dinv, g);
  k_agg<<<NN / 16, 256, 0, stream>>>(g, dinv, b2, row_start, csr_src, h);

  k_pool2<<<NG * PC, 384, 0, stream>>>(h, gstart, partial);
  k_pool3<<<NG, 128, 0, stream>>>(partial, gstart, Wc, bc, out);
}

// Round 6
// 164.589 us; speedup vs baseline: 4.7410x; 1.0291x over previous
//
#include <hip/hip_runtime.h>
#include <hip/hip_fp16.h>

#define NN 50000
#define NE 800000
#define NG 64
#define DF 96
#define SLOPE 0.2f
#define NBK 196   // (NN+255)/256 buckets of 256 dst nodes
#define EB 196    // (NE+4095)/4096 edge blocks
#define PC 12     // pool chunks per graph

// ---------------- pass A1: per-block bucket histogram (no atomics to global) ----------------
__global__ __launch_bounds__(256) void k_hist(const int* __restrict__ dst,
                                              int* __restrict__ hist2d) {
  __shared__ int h[NBK];
  int t = threadIdx.x;
  if (t < NBK) h[t] = 0;
  __syncthreads();
  int base = blockIdx.x * 4096;
  for (int k = 0; k < 16; ++k) {
    int e = base + k * 256 + t;
    if (e < NE) atomicAdd(&h[dst[e] >> 8], 1);
  }
  __syncthreads();
  if (t < NBK) hist2d[blockIdx.x * NBK + t] = h[t];
}

// ---------------- scan: bucket bases + exact per-(block,bucket) offsets ----------------
__global__ __launch_bounds__(256) void k_scanB(const int* __restrict__ hist2d,
                                               int* __restrict__ blockoff,
                                               int* __restrict__ bbase,
                                               const int* __restrict__ batch,
                                               int* __restrict__ gstart,
                                               int* __restrict__ row_start) {
  __shared__ int colsum[256];
  int t = threadIdx.x;
  int s = 0;
  if (t < NBK)
    for (int b = 0; b < EB; ++b) s += hist2d[b * NBK + t];
  colsum[t] = (t < NBK) ? s : 0;
  __syncthreads();
  for (int o = 1; o < 256; o <<= 1) {
    int v = (t >= o) ? colsum[t - o] : 0;
    __syncthreads();
    colsum[t] += v;
    __syncthreads();
  }
  if (t < NBK) {
    int base = (t == 0) ? 0 : colsum[t - 1];
    bbase[t] = base;
    int run = base;
    for (int b = 0; b < EB; ++b) {
      blockoff[b * NBK + t] = run;
      run += hist2d[b * NBK + t];
    }
  }
  if (t == NBK) bbase[NBK] = NE;
  if (t <= NG) {  // graph bounds (batch sorted)
    int g = t, lo = 0, hi = NN;
    while (lo < hi) {
      int mid = (lo + hi) >> 1;
      if (batch[mid] < g) lo = mid + 1; else hi = mid;
    }
    gstart[g] = lo;
  }
  if (t == 255) row_start[NN] = NE;
}

// ---------------- pass A2: bin edges (deterministic offsets, LDS staged) ----------------
// packed entry: src | ((dst&255)<<16)
__global__ __launch_bounds__(256) void k_bin2(const int* __restrict__ src,
                                              const int* __restrict__ dst,
                                              const int* __restrict__ blockoff,
                                              int* __restrict__ binned) {
  __shared__ int h[NBK], loff[NBK], cur[NBK], gb[NBK];
  __shared__ int tmp[256];
  __shared__ int stage[4096];
  __shared__ unsigned char sbk[4096];
  int t = threadIdx.x;
  if (t < NBK) h[t] = 0;
  __syncthreads();
  int base = blockIdx.x * 4096;
  for (int k = 0; k < 16; ++k) {
    int e = base + k * 256 + t;
    if (e < NE) atomicAdd(&h[dst[e] >> 8], 1);
  }
  __syncthreads();
  tmp[t] = (t < NBK) ? h[t] : 0;
  __syncthreads();
  for (int o = 1; o < 256; o <<= 1) {
    int v = (t >= o) ? tmp[t - o] : 0;
    __syncthreads();
    tmp[t] += v;
    __syncthreads();
  }
  if (t < NBK) {
    int excl = (t == 0) ? 0 : tmp[t - 1];
    loff[t] = excl;
    cur[t] = excl;
    gb[t] = blockoff[blockIdx.x * NBK + t];
  }
  __syncthreads();
  for (int k = 0; k < 16; ++k) {
    int e = base + k * 256 + t;
    if (e < NE) {
      int d = dst[e];
      int b = d >> 8;
      int p = atomicAdd(&cur[b], 1);
      stage[p] = src[e] | ((d & 255) << 16);
      sbk[p] = (unsigned char)b;
    }
  }
  __syncthreads();
  int tot = min(4096, NE - base);
  for (int i = t; i < tot; i += 256) {
    int b = sbk[i];
    binned[gb[b] + (i - loff[b])] = stage[i];
  }
}

// ---------------- pass B: per-bucket CSR build + dinv/row_start ----------------
__global__ __launch_bounds__(256) void k_csr(const int* __restrict__ binned,
                                             const int* __restrict__ bbase,
                                             float* __restrict__ dinv,
                                             int* __restrict__ row_start,
                                             unsigned short* __restrict__ csr_src) {
  __shared__ int h[256], cur[256], tmp[256];
  int t = threadIdx.x;
  int b = blockIdx.x;
  int ebeg = bbase[b], eend = bbase[b + 1];
  h[t] = 0;
  __syncthreads();
  for (int i = ebeg + t; i < eend; i += 256) atomicAdd(&h[(unsigned)binned[i] >> 16], 1);
  __syncthreads();
  tmp[t] = h[t];
  __syncthreads();
  for (int o = 1; o < 256; o <<= 1) {
    int v = (t >= o) ? tmp[t - o] : 0;
    __syncthreads();
    tmp[t] += v;
    __syncthreads();
  }
  int excl = (t == 0) ? 0 : tmp[t - 1];
  int rs = ebeg + excl;
  cur[t] = rs;
  int n = b * 256 + t;
  if (n < NN) {
    row_start[n] = rs;
    dinv[n] = rsqrtf((float)h[t] + 1.0f);
  }
  __syncthreads();
  for (int i = ebeg + t; i < eend; i += 256) {
    int pr = binned[i];
    int p = atomicAdd(&cur[(unsigned)pr >> 16], 1);
    csr_src[p] = (unsigned short)(pr & 0xFFFF);
  }
}

// ---------------- G(fp16) = (X @ W) * dinv[row]; X is fp32 or fp16 ----------------
#define GR 64
template <typename T>
__global__ __launch_bounds__(256) void k_gemm(const T* __restrict__ X,
                                              const float* __restrict__ W,
                                              const float* __restrict__ dinv,
                                              __half* __restrict__ G) {
  __shared__ float Ws[DF * DF];
  __shared__ float xs[GR * 100];
  int t = threadIdx.x;
  int rb = blockIdx.x * GR;
  for (int i = t; i < DF * DF / 4; i += 256)
    ((float4*)Ws)[i] = ((const float4*)W)[i];
  for (int i = t; i < GR * DF / 4; i += 256) {
    int r = i / 24, c4 = i % 24;
    int row = rb + r;
    float4 v = {0.f, 0.f, 0.f, 0.f};
    if (row < NN) {
      if constexpr (sizeof(T) == 4) {
        v = ((const float4*)((const float*)X + (size_t)row * DF))[c4];
      } else {
        uint2 hv = ((const uint2*)((const __half*)X + (size_t)row * DF))[c4];
        float2 a = __half22float2(*(__half2*)&hv.x);
        float2 b = __half22float2(*(__half2*)&hv.y);
        v = float4{a.x, a.y, b.x, b.y};
      }
    }
    *(float4*)&xs[r * 100 + c4 * 4] = v;
  }
  __syncthreads();
  int tc = t & 15;
  int tr = t >> 4;
  int c0 = tc * 6;
  int r0 = tr * 4;
  float acc[4][6];
#pragma unroll
  for (int i = 0; i < 4; ++i)
#pragma unroll
    for (int j = 0; j < 6; ++j) acc[i][j] = 0.f;

#pragma unroll 4
  for (int k = 0; k < DF; ++k) {
    float xv[4];
#pragma unroll
    for (int i = 0; i < 4; ++i) xv[i] = xs[(r0 + i) * 100 + k];
    float2 w0 = *(float2*)&Ws[k * DF + c0];
    float2 w1 = *(float2*)&Ws[k * DF + c0 + 2];
    float2 w2 = *(float2*)&Ws[k * DF + c0 + 4];
    float wv[6] = {w0.x, w0.y, w1.x, w1.y, w2.x, w2.y};
#pragma unroll
    for (int i = 0; i < 4; ++i)
#pragma unroll
      for (int j = 0; j < 6; ++j) acc[i][j] = fmaf(xv[i], wv[j], acc[i][j]);
  }
#pragma unroll
  for (int i = 0; i < 4; ++i) {
    int row = rb + r0 + i;
    if (row < NN) {
      float dv = dinv[row];
      __half2* gp = (__half2*)(G + (size_t)row * DF + c0);
#pragma unroll
      for (int j = 0; j < 3; ++j)
        gp[j] = __floats2half2_rn(acc[i][2 * j] * dv, acc[i][2 * j + 1] * dv);
    }
  }
}

// ---------------- gather-aggregate: 16 lanes/node, fp16 in, fp16 out ----------------
__global__ __launch_bounds__(256) void k_agg(const __half* __restrict__ G,
                                             const float* __restrict__ dinv,
                                             const float* __restrict__ bias,
                                             const int* __restrict__ row_start,
                                             const unsigned short* __restrict__ csr_src,
                                             __half* __restrict__ H) {
  int lane = threadIdx.x & 15;
  int n = blockIdx.x * 16 + (threadIdx.x >> 4);
  if (n >= NN) return;
  const unsigned* rn = (const unsigned*)(G + (size_t)n * DF);
  unsigned su0 = rn[lane], su1 = rn[lane + 16], su2 = rn[lane + 32];
  float2 f0 = __half22float2(*(__half2*)&su0);
  float2 f1 = __half22float2(*(__half2*)&su1);
  float2 f2 = __half22float2(*(__half2*)&su2);
  float a00 = f0.x, a01 = f0.y, a10 = f1.x, a11 = f1.y, a20 = f2.x, a21 = f2.y;

  int s = row_start[n], e = row_start[n + 1];
  for (int j0 = s; j0 < e; j0 += 16) {
    int my = (j0 + lane < e) ? (int)csr_src[j0 + lane] : 0;
    int cnt = min(16, e - j0);
    int jj = 0;
    for (; jj + 8 <= cnt; jj += 8) {
      unsigned u[8][3];
#pragma unroll
      for (int q = 0; q < 8; ++q) {
        int srcn = __shfl(my, jj + q, 16);
        const unsigned* r2 = (const unsigned*)(G + (size_t)srcn * DF);
        u[q][0] = r2[lane];
        u[q][1] = r2[lane + 16];
        u[q][2] = r2[lane + 32];
      }
#pragma unroll
      for (int q = 0; q < 8; ++q) {
        float2 g0 = __half22float2(*(__half2*)&u[q][0]);
        float2 g1 = __half22float2(*(__half2*)&u[q][1]);
        float2 g2 = __half22float2(*(__half2*)&u[q][2]);
        a00 += g0.x; a01 += g0.y;
        a10 += g1.x; a11 += g1.y;
        a20 += g2.x; a21 += g2.y;
      }
    }
    for (; jj < cnt; ++jj) {
      int srcn = __shfl(my, jj, 16);
      const unsigned* r2 = (const unsigned*)(G + (size_t)srcn * DF);
      unsigned v0 = r2[lane], v1 = r2[lane + 16], v2 = r2[lane + 32];
      float2 g0 = __half22float2(*(__half2*)&v0);
      float2 g1 = __half22float2(*(__half2*)&v1);
      float2 g2 = __half22float2(*(__half2*)&v2);
      a00 += g0.x; a01 += g0.y;
      a10 += g1.x; a11 += g1.y;
      a20 += g2.x; a21 += g2.y;
    }
  }
  float dv = dinv[n];
  float2 b0 = *(const float2*)(bias + 2 * lane);
  float2 b1 = *(const float2*)(bias + 2 * lane + 32);
  float2 b2 = *(const float2*)(bias + 2 * lane + 64);
  float v00 = dv * a00 + b0.x, v01 = dv * a01 + b0.y;
  float v10 = dv * a10 + b1.x, v11 = dv * a11 + b1.y;
  float v20 = dv * a20 + b2.x, v21 = dv * a21 + b2.y;
  v00 = v00 > 0.f ? v00 : SLOPE * v00;
  v01 = v01 > 0.f ? v01 : SLOPE * v01;
  v10 = v10 > 0.f ? v10 : SLOPE * v10;
  v11 = v11 > 0.f ? v11 : SLOPE * v11;
  v20 = v20 > 0.f ? v20 : SLOPE * v20;
  v21 = v21 > 0.f ? v21 : SLOPE * v21;
  __half2* hp = (__half2*)(H + (size_t)n * DF);
  hp[lane] = __floats2half2_rn(v00, v01);
  hp[lane + 16] = __floats2half2_rn(v10, v11);
  hp[lane + 32] = __floats2half2_rn(v20, v21);
}

// ---------------- pool stage 1: 12 chunks per graph (fp16 in, fp32 partials) ----------------
__global__ __launch_bounds__(384) void k_pool2(const __half* __restrict__ H,
                                               const int* __restrict__ gstart,
                                               float* __restrict__ partial) {
  int g = blockIdx.x / PC, c = blockIdx.x % PC;
  int f2 = threadIdx.x % 48;   // half2 index 0..47
  int r = threadIdx.x / 48;    // 0..7
  int s = gstart[g], e = gstart[g + 1];
  int len = (e - s + PC - 1) / PC;
  int cs = s + c * len, ce = min(cs + len, e);
  float ax = 0.f, ay = 0.f;
  for (int n = cs + r; n < ce; n += 8) {
    float2 v = __half22float2(((const __half2*)(H + (size_t)n * DF))[f2]);
    ax += v.x;
    ay += v.y;
  }
  __shared__ float2 red[8][48];
  red[r][f2] = float2{ax, ay};
  __syncthreads();
  if (r == 0) {
    float sx = 0.f, sy = 0.f;
#pragma unroll
    for (int q = 0; q < 8; ++q) { sx += red[q][f2].x; sy += red[q][f2].y; }
    partial[(size_t)blockIdx.x * DF + 2 * f2] = sx;
    partial[(size_t)blockIdx.x * DF + 2 * f2 + 1] = sy;
  }
}

// ---------------- pool stage 2 + classifier ----------------
__global__ __launch_bounds__(128) void k_pool3(const float* __restrict__ partial,
                                               const int* __restrict__ gstart,
                                               const float* __restrict__ Wc,
                                               const float* __restrict__ bc,
                                               float* __restrict__ out) {
  __shared__ float pm[DF];
  int g = blockIdx.x;
  int t = threadIdx.x;
  if (t < DF) {
    float s = 0.f;
    for (int c = 0; c < PC; ++c) s += partial[(size_t)(g * PC + c) * DF + t];
    float cnt = (float)(gstart[g + 1] - gstart[g]);
    pm[t] = s / fmaxf(cnt, 1.0f);
  }
  __syncthreads();
  if (t < 2) {
    float s = 0.f;
    for (int c = 0; c < DF; ++c) s += pm[c] * Wc[c * 2 + t];
    out[g * 2 + t] = s + bc[t];
  }
}

extern "C" void kernel_launch(void* const* d_in, const int* in_sizes, int n_in,
                              void* d_out, int out_size, void* d_ws, size_t ws_size,
                              hipStream_t stream) {
  const float* x = (const float*)d_in[0];
  const int* ei = (const int*)d_in[1];
  const int* batch = (const int*)d_in[2];
  const float* W1 = (const float*)d_in[3];
  const float* b1 = (const float*)d_in[4];
  const float* W2 = (const float*)d_in[5];
  const float* b2 = (const float*)d_in[6];
  const float* Wc = (const float*)d_in[7];
  const float* bc = (const float*)d_in[8];
  float* out = (float*)d_out;
  const int* srcv = ei;
  const int* dstv = ei + NE;

  char* p = (char*)d_ws;
  auto alloc = [&](size_t bytes) {
    char* r = p;
    p += (bytes + 255) & ~(size_t)255;
    return r;
  };
  int* hist2d = (int*)alloc((size_t)EB * NBK * sizeof(int));
  int* blockoff = (int*)alloc((size_t)EB * NBK * sizeof(int));
  int* bbase = (int*)alloc((size_t)(NBK + 1) * sizeof(int));
  int* gstart = (int*)alloc((size_t)(NG + 1) * sizeof(int));
  int* row_start = (int*)alloc((size_t)(NN + 1) * sizeof(int));
  int* binned = (int*)alloc((size_t)NE * sizeof(int));
  unsigned short* csr_src = (unsigned short*)alloc((size_t)NE * sizeof(unsigned short));
  float* dinv = (float*)alloc((size_t)NN * sizeof(float));
  __half* g = (__half*)alloc((size_t)NN * DF * sizeof(__half));
  __half* h = (__half*)alloc((size_t)NN * DF * sizeof(__half));
  float* partial = (float*)alloc((size_t)NG * PC * DF * sizeof(float));

  k_hist<<<EB, 256, 0, stream>>>(dstv, hist2d);
  k_scanB<<<1, 256, 0, stream>>>(hist2d, blockoff, bbase, batch, gstart, row_start);
  k_bin2<<<EB, 256, 0, stream>>>(srcv, dstv, blockoff, binned);
  k_csr<<<NBK, 256, 0, stream>>>(binned, bbase, dinv, row_start, csr_src);

  k_gemm<float><<<(NN + GR - 1) / GR, 256, 0, stream>>>(x, W1, dinv, g);
  k_agg<<<NN / 16, 256, 0, stream>>>(g, dinv, b1, row_start, csr_src, h);
  k_gemm<__half><<<(NN + GR - 1) / GR, 256, 0, stream>>>(h, W2, dinv, g);
  k_agg<<<NN / 16, 256, 0, stream>>>(g, dinv, b2, row_start, csr_src, h);

  k_pool2<<<NG * PC, 384, 0, stream>>>(h, gstart, partial);
  k_pool3<<<NG, 128, 0, stream>>>(partial, gstart, Wc, bc, out);
}